// Round 4
// baseline (239.075 us; speedup 1.0000x reference)
//
#include <hip/hip_runtime.h>

typedef __attribute__((ext_vector_type(8))) short short8;
typedef __attribute__((ext_vector_type(8))) unsigned short ushort8;
typedef __attribute__((ext_vector_type(4))) float f32x4;

__device__ __forceinline__ float bf2f(unsigned short u) {
  union { unsigned int u; float f; } c; c.u = ((unsigned int)u) << 16; return c.f;
}
__device__ __forceinline__ unsigned short f2bf(float f) {
  union { float f; unsigned int u; } c; c.f = f;
  unsigned int x = c.u;
  return (unsigned short)((x + 0x7FFFu + ((x >> 16) & 1u)) >> 16);
}

#define GLD_LDS16(g, l)                                                        \
  __builtin_amdgcn_global_load_lds(                                            \
      (const __attribute__((address_space(1))) void*)(g),                      \
      (__attribute__((address_space(3))) void*)(l), 16, 0, 0)

__device__ __forceinline__ void bar() {
  asm volatile("" ::: "memory");
  __builtin_amdgcn_s_barrier();
  asm volatile("" ::: "memory");
}

// --------------------------------------------------- fused prep:
// [0,4096): cast X fp32 -> bf16
// [4096,4864): transpose+cast W[1024][3072] -> Wt[3072][1024] bf16
// 4864: zero Lrow
__global__ __launch_bounds__(256) void prep_kernel(
    const float* __restrict__ X, unsigned short* __restrict__ Xb,
    const float* __restrict__ W, unsigned short* __restrict__ Wt,
    float* __restrict__ Lrow) {
  const int t = threadIdx.x;
  if (blockIdx.x < 4096) {
    long i = ((long)blockIdx.x * 256 + t) * 8;
    float4 a = *(const float4*)(X + i);
    float4 b = *(const float4*)(X + i + 4);
    ushort8 o;
    o[0] = f2bf(a.x); o[1] = f2bf(a.y); o[2] = f2bf(a.z); o[3] = f2bf(a.w);
    o[4] = f2bf(b.x); o[5] = f2bf(b.y); o[6] = f2bf(b.z); o[7] = f2bf(b.w);
    *(ushort8*)(Xb + i) = o;
  } else if (blockIdx.x < 4864) {
    const int bid = blockIdx.x - 4096;          // 768 blocks = 48 x 16
    const int f0 = (bid % 48) * 64;
    const int e0 = (bid / 48) * 64;
    __shared__ unsigned short tile[64][65];
    const int cg = (t & 15) * 4;
    const int r = t >> 4;
#pragma unroll
    for (int i = 0; i < 4; ++i) {
      int e = r + i * 16;
      float4 v = *(const float4*)(W + (long)(e0 + e) * 3072 + f0 + cg);
      tile[e][cg + 0] = f2bf(v.x);
      tile[e][cg + 1] = f2bf(v.y);
      tile[e][cg + 2] = f2bf(v.z);
      tile[e][cg + 3] = f2bf(v.w);
    }
    __syncthreads();
#pragma unroll
    for (int i = 0; i < 4; ++i) {
      int f = (t >> 4) + i * 16;
      int e = (t & 15) * 4;
      ushort4 o;
      o.x = tile[e + 0][f];
      o.y = tile[e + 1][f];
      o.z = tile[e + 2][f];
      o.w = tile[e + 3][f];
      *(ushort4*)(Wt + (long)(f0 + f) * 1024 + e0 + e) = o;
    }
  } else {
    float4 z = {0.f, 0.f, 0.f, 0.f};
#pragma unroll
    for (int j = 0; j < 8; ++j) *(float4*)(Lrow + (j * 256 + t) * 4) = z;
  }
}

// ================================================================
// 256x256 GEMM (C = A * B^T), BK=64, 512 threads, 8 waves, 4 phases/tile.
// R4 structure: fragment reads pipelined ONE PHASE AHEAD with counted
// lgkmcnt so the LDS pipe (~580 cy/phase) overlaps the MFMA pipes
// (~620 cy/phase) instead of serializing (R3 measured 1368 cy/phase).
// One barrier per phase.
//
// LDS (128 KiB), per buffer: A[256][64] | B[256][64] bf16, 128 B rows,
// m97 XOR-8 slot swizzle (slot s of row r holds k-chunk s^(r&7));
// staged linear-dest global_load_lds with pre-swizzled per-lane source.
// Stage unit j = rows j*64+wave*8..+7 (1 GLD/wave); A units {0,2}=mh0,
// {1,3}=mh1 rows.
//
// Per-tile ledger (phase p issues reads for MFMA p+1):
//   p0: rd aN=A.mh1.ks0(buf)[4] | stage T+1: A0,A2,B0..B3 -> nbuf
//       bar; lgkm(4); MFMA0(aC,bC -> acc[0..3])
//   p1: rd aC=A.mh0.ks1, bN=B.ks1 (buf)[8] | stage T+1: A1,A3
//       bar; lgkm(8); MFMA1(aN,bC -> acc[4..7])
//   p2: rd aN=A.mh1.ks1(buf)[4] | vmcnt(2) [drains p0's 6]
//       bar; lgkm(4); MFMA2(aC,bN -> acc[0..3])
//   p3: rd aC=A.mh0.ks0, bC=B.ks0 (NBUF)[8] | vmcnt(0) [drains p1's 2]
//       bar; lgkm(8); MFMA3(aN,bN -> acc[4..7])
// Sync proofs: nbuf regions read at p3 (A{0,2},B) land at p2's vmcnt(2)+bar;
// A{1,3} land at p3's vmcnt(0)+bar, read at T+1.p0. Stage-into-region is >=1
// barrier after ALL waves' draining lgkm of that region's last read
// (death lgkm(q) -> stage at q+2): buf A{0,2},B die lgkm(p2) -> staged T+1.p0;
// A{1,3} die lgkm(p3) -> staged T+1.p1. vmcnt waits have >=2-phase cover.
// MODE 0 (qkv): bx<8 -> bf16 to QK; bx>=8 -> LDS-transpose -> Vt.
// MODE 1 (score): bf16 exp(acc*alpha) + row-sum atomicAdd into Lrow.
// ================================================================
template <int MODE>
__device__ __forceinline__ void gemm256_body(
    const unsigned short* __restrict__ A, const unsigned short* __restrict__ B,
    void* __restrict__ Cv, int K, int lda, int ldb, int ldc,
    long sA, long sB, long sC, float alpha, float* __restrict__ Lrow,
    unsigned short* __restrict__ Vt) {
  __shared__ __align__(16) unsigned short smem[65536];  // 128 KiB

  const int t = threadIdx.x;
  const int lane = t & 63;
  const int wave = t >> 6;        // 0..7
  const int quad = lane >> 4;     // 0..3
  const int mrow = lane & 15;     // 0..15
  const int wm = wave >> 2;       // 0..1  (M half)
  const int wn = wave & 3;        // 0..3  (N quarter)

  const int bx = blockIdx.x, by = blockIdx.y, b = blockIdx.z;
  const int rowA0 = by * 256;
  const int rowB0 = bx * 256;
  const unsigned short* Ab = A + (long)b * sA;
  const unsigned short* Bb = B + (long)b * sB;

  // staging: lane l -> row (l>>3), phys slot l&7 holds k-chunk (l&7)^(l>>3)
  const int srow = lane >> 3;                 // 0..7
  const int scol = ((lane & 7) ^ srow) * 8;   // pre-swizzled source col

  // hoisted per-unit global base pointers (unit j = rows j*64+wave*8..+7)
  const unsigned short* gA[4];
  const unsigned short* gB[4];
#pragma unroll
  for (int j = 0; j < 4; ++j) {
    gA[j] = Ab + (long)(rowA0 + j * 64 + wave * 8 + srow) * lda + scol;
    gB[j] = Bb + (long)(rowB0 + j * 64 + wave * 8 + srow) * ldb + scol;
  }
  const int dst = wave * 512;  // + j*4096 within a region

  f32x4 acc[8][4];
#pragma unroll
  for (int i = 0; i < 8; ++i)
#pragma unroll
    for (int j = 0; j < 4; ++j) {
      f32x4 z = {0.f, 0.f, 0.f, 0.f};
      acc[i][j] = z;
    }

  const int NT = K >> 6;  // >= 2 required

  const int m7 = mrow & 7;
  const int aslot0 = (quad ^ m7) * 8;  // ks=0 slot (elems); ks=1: ^32
  const int arow0 = (wm * 128 + mrow) * 64;        // A mh0 row base (elems)
  const int brow0 = (wn * 64 + mrow) * 64;         // B row base

  short8 aC[4], aN[4], bC[4], bN[4];

  // ---- prologue: stage T0 fully; pre-read MFMA0 frags (aC,bC) ----
  {
#pragma unroll
    for (int j = 0; j < 4; ++j) GLD_LDS16(gA[j], smem + j * 4096 + dst);
#pragma unroll
    for (int j = 0; j < 4; ++j)
      GLD_LDS16(gB[j], smem + 16384 + j * 4096 + dst);
    asm volatile("s_waitcnt vmcnt(0)" ::: "memory");
    bar();
#pragma unroll
    for (int i = 0; i < 4; ++i)
      aC[i] = *(const short8*)(smem + arow0 + i * 1024 + aslot0);
#pragma unroll
    for (int j = 0; j < 4; ++j)
      bC[j] = *(const short8*)(smem + 16384 + brow0 + j * 1024 + aslot0);
  }

  for (int T = 0; T < NT; ++T) {
    const int boff = (T & 1) << 15;  // 0 / 32768 elems
    const int noff = boff ^ 32768;
    const unsigned short* As = smem + boff;
    const unsigned short* Bs = smem + boff + 16384;
    const unsigned short* Asn = smem + noff;
    const unsigned short* Bsn = smem + noff + 16384;
    const int kt1 = (T + 1) << 6;
    const bool more = (T + 1) < NT;

    // ---------------- p0 ----------------
#pragma unroll
    for (int i = 0; i < 4; ++i)
      aN[i] = *(const short8*)(As + arow0 + 4096 + i * 1024 + aslot0);
    if (more) {
      GLD_LDS16(gA[0] + kt1, smem + noff + 0 * 4096 + dst);
      GLD_LDS16(gA[2] + kt1, smem + noff + 2 * 4096 + dst);
      GLD_LDS16(gB[0] + kt1, smem + noff + 16384 + 0 * 4096 + dst);
      GLD_LDS16(gB[1] + kt1, smem + noff + 16384 + 1 * 4096 + dst);
      GLD_LDS16(gB[2] + kt1, smem + noff + 16384 + 2 * 4096 + dst);
      GLD_LDS16(gB[3] + kt1, smem + noff + 16384 + 3 * 4096 + dst);
    }
    bar();
    asm volatile("s_waitcnt lgkmcnt(4)" ::: "memory");
    __builtin_amdgcn_sched_barrier(0);
    __builtin_amdgcn_s_setprio(1);
#pragma unroll
    for (int i = 0; i < 4; ++i)
#pragma unroll
      for (int j = 0; j < 4; ++j)
        acc[i][j] = __builtin_amdgcn_mfma_f32_16x16x32_bf16(aC[i], bC[j],
                                                            acc[i][j], 0, 0, 0);
    __builtin_amdgcn_s_setprio(0);

    // ---------------- p1 ----------------
#pragma unroll
    for (int i = 0; i < 4; ++i)
      aC[i] = *(const short8*)(As + arow0 + i * 1024 + (aslot0 ^ 32));
#pragma unroll
    for (int j = 0; j < 4; ++j)
      bN[j] = *(const short8*)(Bs + brow0 + j * 1024 + (aslot0 ^ 32));
    if (more) {
      GLD_LDS16(gA[1] + kt1, smem + noff + 1 * 4096 + dst);
      GLD_LDS16(gA[3] + kt1, smem + noff + 3 * 4096 + dst);
    }
    bar();
    asm volatile("s_waitcnt lgkmcnt(8)" ::: "memory");
    __builtin_amdgcn_sched_barrier(0);
    __builtin_amdgcn_s_setprio(1);
#pragma unroll
    for (int i = 0; i < 4; ++i)
#pragma unroll
      for (int j = 0; j < 4; ++j)
        acc[4 + i][j] = __builtin_amdgcn_mfma_f32_16x16x32_bf16(
            aN[i], bC[j], acc[4 + i][j], 0, 0, 0);
    __builtin_amdgcn_s_setprio(0);

    // ---------------- p2 ----------------
#pragma unroll
    for (int i = 0; i < 4; ++i)
      aN[i] = *(const short8*)(As + arow0 + 4096 + i * 1024 + (aslot0 ^ 32));
    if (more) asm volatile("s_waitcnt vmcnt(2)" ::: "memory");
    bar();
    asm volatile("s_waitcnt lgkmcnt(4)" ::: "memory");
    __builtin_amdgcn_sched_barrier(0);
    __builtin_amdgcn_s_setprio(1);
#pragma unroll
    for (int i = 0; i < 4; ++i)
#pragma unroll
      for (int j = 0; j < 4; ++j)
        acc[i][j] = __builtin_amdgcn_mfma_f32_16x16x32_bf16(aC[i], bN[j],
                                                            acc[i][j], 0, 0, 0);
    __builtin_amdgcn_s_setprio(0);

    // ---------------- p3 ----------------
    if (more) {
#pragma unroll
      for (int i = 0; i < 4; ++i)
        aC[i] = *(const short8*)(Asn + arow0 + i * 1024 + aslot0);
#pragma unroll
      for (int j = 0; j < 4; ++j)
        bC[j] = *(const short8*)(Bsn + brow0 + j * 1024 + aslot0);
      asm volatile("s_waitcnt vmcnt(0)" ::: "memory");
    }
    bar();
    if (more) {
      asm volatile("s_waitcnt lgkmcnt(8)" ::: "memory");
    } else {
      asm volatile("s_waitcnt lgkmcnt(0)" ::: "memory");
    }
    __builtin_amdgcn_sched_barrier(0);
    __builtin_amdgcn_s_setprio(1);
#pragma unroll
    for (int i = 0; i < 4; ++i)
#pragma unroll
      for (int j = 0; j < 4; ++j)
        acc[4 + i][j] = __builtin_amdgcn_mfma_f32_16x16x32_bf16(
            aN[i], bN[j], acc[4 + i][j], 0, 0, 0);
    __builtin_amdgcn_s_setprio(0);
  }

  // -------------------- epilogue --------------------
  const long cb = (long)b * sC;

  if constexpr (MODE == 0) {
    if (bx < 8) {
      unsigned short* C = (unsigned short*)Cv;
#pragma unroll
      for (int m = 0; m < 8; ++m) {
        int row = rowA0 + wm * 128 + m * 16 + quad * 4;
#pragma unroll
        for (int j = 0; j < 4; ++j) {
          int col = rowB0 + wn * 64 + j * 16 + mrow;
#pragma unroll
          for (int r = 0; r < 4; ++r)
            C[(long)(row + r) * ldc + col] = f2bf(acc[m][j][r]);
        }
      }
    } else {
      // V: transpose via LDS (smem reused as [e 256][s 256] bf16, 128 KiB)
      // swz bits 3-6 only -> 4-aligned ushort4 writes / 8-aligned ushort8 reads
      bar();  // all waves past final lgkm before smem reuse
#pragma unroll
      for (int m = 0; m < 8; ++m) {
        int s4 = wm * 128 + m * 16 + quad * 4;
#pragma unroll
        for (int j = 0; j < 4; ++j) {
          int e = wn * 64 + j * 16 + mrow;
          int swz = ((e & 7) << 4) ^ (((e >> 3) & 3) << 3);
          ushort4 pk;
          pk.x = f2bf(acc[m][j][0]);
          pk.y = f2bf(acc[m][j][1]);
          pk.z = f2bf(acc[m][j][2]);
          pk.w = f2bf(acc[m][j][3]);
          *(ushort4*)(smem + e * 256 + (s4 ^ swz)) = pk;
        }
      }
      __syncthreads();
      const int batch = by >> 3;
      const int s_base = (by & 7) * 256;
      const int e_base = (bx - 8) * 256;
      unsigned short* VtB = Vt + (long)batch * 1024 * 2048;
      const int er = t >> 5;          // 0..15
      const int s = (t & 31) * 8;     // 0..248
#pragma unroll
      for (int rnd = 0; rnd < 16; ++rnd) {
        int e = rnd * 16 + er;
        int swz = ((e & 7) << 4) ^ (((e >> 3) & 3) << 3);
        ushort8 v = *(const ushort8*)(smem + e * 256 + (s ^ swz));
        *(ushort8*)(VtB + (long)(e_base + e) * 2048 + s_base + s) = v;
      }
    }
  } else {
    // MODE 1: E = exp(acc*alpha) -> bf16; row sums -> Lrow
    unsigned short* C = (unsigned short*)Cv;
    float p[8][4];
#pragma unroll
    for (int m = 0; m < 8; ++m)
#pragma unroll
      for (int r = 0; r < 4; ++r) p[m][r] = 0.f;
#pragma unroll
    for (int m = 0; m < 8; ++m) {
      int row = rowA0 + wm * 128 + m * 16 + quad * 4;
#pragma unroll
      for (int j = 0; j < 4; ++j) {
        int col = rowB0 + wn * 64 + j * 16 + mrow;
#pragma unroll
        for (int r = 0; r < 4; ++r) {
          float e = __expf(acc[m][j][r] * alpha);
          C[cb + (long)(row + r) * ldc + col] = f2bf(e);
          p[m][r] += e;
        }
      }
    }
#pragma unroll
    for (int off = 1; off < 16; off <<= 1)
#pragma unroll
      for (int m = 0; m < 8; ++m)
#pragma unroll
        for (int r = 0; r < 4; ++r)
          p[m][r] += __shfl_xor(p[m][r], off, 64);
    if (mrow == 0) {
#pragma unroll
      for (int m = 0; m < 8; ++m) {
        int row = rowA0 + wm * 128 + m * 16 + quad * 4;
#pragma unroll
        for (int r = 0; r < 4; ++r)
          atomicAdd(&Lrow[b * 2048 + row + r], p[m][r]);
      }
    }
  }
}

// ---------------------------------------------------------------- m97 body,
// kept for the out GEMM (MODE 2 only: fp32 store of acc/Lrow[row]).
template <int MODE>
__device__ __forceinline__ void gemm_body(
    const unsigned short* __restrict__ A, const unsigned short* __restrict__ B,
    void* __restrict__ Cv, int K, int lda, int ldb, int ldc,
    long sA, long sB, long sC, float alpha, float* __restrict__ Lrow,
    unsigned short* __restrict__ Vt) {
  constexpr int BM = 128, BN = 128, BK = 64;
  __shared__ __align__(16) unsigned short smem[BM * BK + BN * BK];  // 32 KB
  unsigned short* As = smem;
  unsigned short* Bs = smem + BM * BK;

  const int t = threadIdx.x;
  const int lane = t & 63;
  const int wave = t >> 6;
  const int quad = lane >> 4;
  const int mrow = lane & 15;
  const int wm = wave >> 1, wn = wave & 1;

  const int bx = blockIdx.x, by = blockIdx.y;
  const int rowA0 = by * BM;
  const int rowB0 = bx * BN;
  const int b = blockIdx.z;
  const unsigned short* Ab = A + (long)b * sA;
  const unsigned short* Bb = B + (long)b * sB;

  f32x4 acc[4][4];
#pragma unroll
  for (int i = 0; i < 4; ++i)
#pragma unroll
    for (int j = 0; j < 4; ++j) {
      f32x4 z = {0.f, 0.f, 0.f, 0.f};
      acc[i][j] = z;
    }

  const int rbase = wave * 32 + (lane >> 3);
  const int c2 = lane & 7;

  for (int kt = 0; kt < K; kt += BK) {
#pragma unroll
    for (int j = 0; j < 4; ++j) {
      int r = rbase + j * 8;
      int c = c2 ^ (r & 7);
      GLD_LDS16(Ab + (long)(rowA0 + r) * lda + kt + c * 8, As + (wave * 4 + j) * 512);
      GLD_LDS16(Bb + (long)(rowB0 + r) * ldb + kt + c * 8, Bs + (wave * 4 + j) * 512);
    }
    __syncthreads();
#pragma unroll
    for (int ks = 0; ks < 2; ++ks) {
      short8 af[4], bfr[4];
#pragma unroll
      for (int i = 0; i < 4; ++i) {
        int rA = wm * 64 + i * 16 + mrow;
        int cc = ks * 4 + quad;
        af[i] = *(const short8*)(As + (rA * 8 + (cc ^ (rA & 7))) * 8);
        int rB = wn * 64 + i * 16 + mrow;
        bfr[i] = *(const short8*)(Bs + (rB * 8 + (cc ^ (rB & 7))) * 8);
      }
#pragma unroll
      for (int mt = 0; mt < 4; ++mt)
#pragma unroll
        for (int nt = 0; nt < 4; ++nt)
          acc[mt][nt] = __builtin_amdgcn_mfma_f32_16x16x32_bf16(
              af[mt], bfr[nt], acc[mt][nt], 0, 0, 0);
    }
    __syncthreads();
  }

  const int m_base = rowA0 + wm * 64;
  const int n_base = rowB0 + wn * 64;
  const long cb = (long)b * sC;

  // MODE 2 only instantiated: fp32 out, scaled by 1/Lrow[row]
#pragma unroll
  for (int mt = 0; mt < 4; ++mt)
#pragma unroll
    for (int i = 0; i < 4; ++i) {
      int row = m_base + mt * 16 + quad * 4 + i;
      float inv = 1.0f / Lrow[b * 2048 + row];
#pragma unroll
      for (int nt = 0; nt < 4; ++nt) {
        int col = n_base + nt * 16 + mrow;
        ((float*)Cv)[cb + (long)row * ldc + col] = acc[mt][nt][i] * inv;
      }
    }
}

// distinct names so rocprof separates the three GEMMs
__global__ __launch_bounds__(512, 2) void qkv_gemm_kernel(
    const unsigned short* __restrict__ A, const unsigned short* __restrict__ B,
    void* __restrict__ Cv, int K, int lda, int ldb, int ldc,
    long sA, long sB, long sC, float alpha, float* __restrict__ Lrow,
    unsigned short* __restrict__ Vt) {
  gemm256_body<0>(A, B, Cv, K, lda, ldb, ldc, sA, sB, sC, alpha, Lrow, Vt);
}
__global__ __launch_bounds__(512, 2) void score_gemm_kernel(
    const unsigned short* __restrict__ A, const unsigned short* __restrict__ B,
    void* __restrict__ Cv, int K, int lda, int ldb, int ldc,
    long sA, long sB, long sC, float alpha, float* __restrict__ Lrow,
    unsigned short* __restrict__ Vt) {
  gemm256_body<1>(A, B, Cv, K, lda, ldb, ldc, sA, sB, sC, alpha, Lrow, Vt);
}
__global__ __launch_bounds__(256, 2) void out_gemm_kernel(
    const unsigned short* __restrict__ A, const unsigned short* __restrict__ B,
    void* __restrict__ Cv, int K, int lda, int ldb, int ldc,
    long sA, long sB, long sC, float alpha, float* __restrict__ Lrow,
    unsigned short* __restrict__ Vt) {
  gemm_body<2>(A, B, Cv, K, lda, ldb, ldc, sA, sB, sC, alpha, Lrow, Vt);
}

// ---------------------------------------------------------------- launch
extern "C" void kernel_launch(void* const* d_in, const int* in_sizes, int n_in,
                              void* d_out, int out_size, void* d_ws, size_t ws_size,
                              hipStream_t stream) {
  const float* X = (const float*)d_in[0];  // [4,2048,1024] fp32
  const float* W = (const float*)d_in[1];  // [1024,3072] fp32
  float* out = (float*)d_out;              // [4,2048,1024] fp32

  char* ws = (char*)d_ws;
  unsigned short* Xb  = (unsigned short*)(ws);                 // 8192x1024 bf16   (16 MiB)
  unsigned short* Wtb = (unsigned short*)(ws + 16777216);      // 3072x1024 bf16   ( 6 MiB)
  unsigned short* QK  = (unsigned short*)(ws + 23068672);      // 8192x2048 bf16   (32 MiB)
  unsigned short* Vt  = (unsigned short*)(ws + 56623104);      // 4x1024x2048 bf16 (16 MiB)
  unsigned short* Sb  = (unsigned short*)(ws + 73400320);      // 4x2048x2048 bf16 (32 MiB)
  float* Lrow         = (float*)(ws + 106954752);              // 4x2048 fp32      (32 KiB)

  // 1. prep: cast X, transpose W, zero Lrow
  prep_kernel<<<4865, 256, 0, stream>>>(X, Xb, W, Wtb, Lrow);

  // 2. [Q|K] = Xb @ Wtb^T  (bx<8 -> QK, ldc=2048); V -> Vt transposed (bx>=8)
  qkv_gemm_kernel<<<dim3(12, 32, 1), 512, 0, stream>>>(
      Xb, Wtb, QK, 1024, 1024, 1024, 2048, 0L, 0L, 0L, 1.0f, nullptr, Vt);

  // 3. E = exp(Q @ K^T / 32) per batch [2048 x 2048], K=1024; row sums -> Lrow
  score_gemm_kernel<<<dim3(8, 8, 4), 512, 0, stream>>>(
      QK, QK + 1024, Sb, 1024, 2048, 2048, 2048,
      (long)2048 * 2048, (long)2048 * 2048, (long)2048 * 2048, 0.03125f, Lrow, nullptr);

  // 4. O = (E @ Vt^T) / L  per batch  [2048 x 1024], K=2048 -> fp32 out
  out_gemm_kernel<<<dim3(8, 16, 4), 256, 0, stream>>>(
      Sb, Vt, out, 2048, 2048, 2048, 1024,
      (long)2048 * 2048, (long)1024 * 2048, (long)2048 * 1024, 1.0f, Lrow, nullptr);
}

// Round 5
// 238.448 us; speedup vs baseline: 1.0026x; 1.0026x over previous
//
#include <hip/hip_runtime.h>

typedef __attribute__((ext_vector_type(8))) short short8;
typedef __attribute__((ext_vector_type(8))) unsigned short ushort8;
typedef __attribute__((ext_vector_type(4))) float f32x4;

__device__ __forceinline__ float bf2f(unsigned short u) {
  union { unsigned int u; float f; } c; c.u = ((unsigned int)u) << 16; return c.f;
}
__device__ __forceinline__ unsigned short f2bf(float f) {
  union { float f; unsigned int u; } c; c.f = f;
  unsigned int x = c.u;
  return (unsigned short)((x + 0x7FFFu + ((x >> 16) & 1u)) >> 16);
}

#define GLD_LDS16(g, l)                                                        \
  __builtin_amdgcn_global_load_lds(                                            \
      (const __attribute__((address_space(1))) void*)(g),                      \
      (__attribute__((address_space(3))) void*)(l), 16, 0, 0)

__device__ __forceinline__ void bar() {
  asm volatile("" ::: "memory");
  __builtin_amdgcn_s_barrier();
  asm volatile("" ::: "memory");
}

// --------------------------------------------------- fused prep:
// [0,4096): cast X fp32 -> bf16
// [4096,4864): transpose+cast W[1024][3072] -> Wt[3072][1024] bf16
// 4864: zero Lrow
__global__ __launch_bounds__(256) void prep_kernel(
    const float* __restrict__ X, unsigned short* __restrict__ Xb,
    const float* __restrict__ W, unsigned short* __restrict__ Wt,
    float* __restrict__ Lrow) {
  const int t = threadIdx.x;
  if (blockIdx.x < 4096) {
    long i = ((long)blockIdx.x * 256 + t) * 8;
    float4 a = *(const float4*)(X + i);
    float4 b = *(const float4*)(X + i + 4);
    ushort8 o;
    o[0] = f2bf(a.x); o[1] = f2bf(a.y); o[2] = f2bf(a.z); o[3] = f2bf(a.w);
    o[4] = f2bf(b.x); o[5] = f2bf(b.y); o[6] = f2bf(b.z); o[7] = f2bf(b.w);
    *(ushort8*)(Xb + i) = o;
  } else if (blockIdx.x < 4864) {
    const int bid = blockIdx.x - 4096;          // 768 blocks = 48 x 16
    const int f0 = (bid % 48) * 64;
    const int e0 = (bid / 48) * 64;
    __shared__ unsigned short tile[64][65];
    const int cg = (t & 15) * 4;
    const int r = t >> 4;
#pragma unroll
    for (int i = 0; i < 4; ++i) {
      int e = r + i * 16;
      float4 v = *(const float4*)(W + (long)(e0 + e) * 3072 + f0 + cg);
      tile[e][cg + 0] = f2bf(v.x);
      tile[e][cg + 1] = f2bf(v.y);
      tile[e][cg + 2] = f2bf(v.z);
      tile[e][cg + 3] = f2bf(v.w);
    }
    __syncthreads();
#pragma unroll
    for (int i = 0; i < 4; ++i) {
      int f = (t >> 4) + i * 16;
      int e = (t & 15) * 4;
      ushort4 o;
      o.x = tile[e + 0][f];
      o.y = tile[e + 1][f];
      o.z = tile[e + 2][f];
      o.w = tile[e + 3][f];
      *(ushort4*)(Wt + (long)(f0 + f) * 1024 + e0 + e) = o;
    }
  } else {
    float4 z = {0.f, 0.f, 0.f, 0.f};
#pragma unroll
    for (int j = 0; j < 8; ++j) *(float4*)(Lrow + (j * 256 + t) * 4) = z;
  }
}

// ================================================================
// 256x256 GEMM (C = A * B^T), BK=64, 512 threads, 8 waves, 4 phases/tile.
// R5: faithful m201 cadence. Per phase:
//   {4|8 ds_reads (this phase's frags); 2 GLD (one half-tile); bar;
//    lgkmcnt(0); sched_barrier; setprio(1); 16 MFMA; setprio(0)}
// + ONE vmcnt + bar per tile (at p3 end). LDS/MFMA overlap comes from
// cross-wave stagger of lgkmcnt(0) completion (m201's verified mechanism).
//
// LDS (128 KiB), per buffer: A[256][64] | B[256][64] bf16, 128 B rows,
// m97 XOR-8 slot swizzle (slot s of row r holds k-chunk s^(r&7)); staged
// via linear-dest global_load_lds, pre-swizzled per-lane source col.
// Half-tile = 128 rows = 2 GLD/wave. Regions per buffer: A-h0|A-h1|B-h0|B-h1.
//
// Ledger (tile T, cur=buf[T&1], nxt=other):
//   reads: wave wm reads A-h{wm} at all 4 phases (ks0: p0 mh-local0/p1 local1;
//          ks1: p2/p3); wave wn reads its B quarter at p0 (ks0) & p2 (ks1).
//   deaths: B-h0,B-h1 die p2; A-h0,A-h1 die p3.
//   stages: p0: A-h0(T+1)->nxt  p1: A-h1(T+1)->nxt  p2: B-h1(T+1)->nxt
//           p3: B-h0(T+2)->cur [B dead since p2, >=1 bar]
//   (B-h0(T+1) was staged at T-1.p3 / prologue -> covers 5 phases.)
//   tile end: vmcnt(2) [in-order retire drains through p2's stage; leaves
//   p3's 2] + bar -> all of T+1's data landed & visible to ALL waves before
//   T+1.p0's ds_reads (fixes R4's per-wave-vmcnt visibility race).
//   Tail: stages guarded; vmcnt(0) when T+2>=NT -> zero in flight at loop end.
// MODE 0 (qkv): bx<8 -> bf16 to QK; bx>=8 -> LDS-transpose -> Vt.
// MODE 1 (score): bf16 exp(acc*alpha) + row-sum atomicAdd into Lrow.
// ================================================================
template <int MODE>
__device__ __forceinline__ void gemm256_body(
    const unsigned short* __restrict__ A, const unsigned short* __restrict__ B,
    void* __restrict__ Cv, int K, int lda, int ldb, int ldc,
    long sA, long sB, long sC, float alpha, float* __restrict__ Lrow,
    unsigned short* __restrict__ Vt) {
  __shared__ __align__(16) unsigned short smem[65536];  // 128 KiB

  const int t = threadIdx.x;
  const int lane = t & 63;
  const int wave = t >> 6;        // 0..7
  const int quad = lane >> 4;     // 0..3
  const int mrow = lane & 15;     // 0..15
  const int wm = wave >> 2;       // 0..1  (M half)
  const int wn = wave & 3;        // 0..3  (N quarter)

  const int bx = blockIdx.x, by = blockIdx.y, b = blockIdx.z;
  const int rowA0 = by * 256;
  const int rowB0 = bx * 256;
  const unsigned short* Ab = A + (long)b * sA;
  const unsigned short* Bb = B + (long)b * sB;

  // staging: lane l -> row (l>>3), phys slot l&7 holds k-chunk (l&7)^(l>>3)
  const int srow = lane >> 3;
  const int scol = ((lane & 7) ^ srow) * 8;

  // per (half h, gld g) global base: rows h*128 + wave*16 + g*8 + srow
  const unsigned short* gA[2][2];
  const unsigned short* gB[2][2];
#pragma unroll
  for (int h = 0; h < 2; ++h)
#pragma unroll
    for (int g = 0; g < 2; ++g) {
      gA[h][g] =
          Ab + (long)(rowA0 + h * 128 + wave * 16 + g * 8 + srow) * lda + scol;
      gB[h][g] =
          Bb + (long)(rowB0 + h * 128 + wave * 16 + g * 8 + srow) * ldb + scol;
    }
  const int dsth = wave * 1024;  // (wave*16)*64 elems within a half region

  f32x4 acc[8][4];
#pragma unroll
  for (int i = 0; i < 8; ++i)
#pragma unroll
    for (int j = 0; j < 4; ++j) {
      f32x4 z = {0.f, 0.f, 0.f, 0.f};
      acc[i][j] = z;
    }

  const int NT = K >> 6;

  // stage half h of A/B for k-offset kt into buffer elem-offset boff
  auto stgA = [&](int h, int kt, int boff) {
    GLD_LDS16(gA[h][0] + kt, smem + boff + h * 8192 + dsth);
    GLD_LDS16(gA[h][1] + kt, smem + boff + h * 8192 + dsth + 512);
  };
  auto stgB = [&](int h, int kt, int boff) {
    GLD_LDS16(gB[h][0] + kt, smem + boff + 16384 + h * 8192 + dsth);
    GLD_LDS16(gB[h][1] + kt, smem + boff + 16384 + h * 8192 + dsth + 512);
  };

  // ---- prologue: T0 fully; B-h0(T1) into buf1 (the T-1.p3 slot) ----
  stgA(0, 0, 0);
  stgA(1, 0, 0);
  stgB(0, 0, 0);
  stgB(1, 0, 0);
  if (NT > 1) {
    stgB(0, 64, 32768);
    asm volatile("s_waitcnt vmcnt(2)" ::: "memory");
  } else {
    asm volatile("s_waitcnt vmcnt(0)" ::: "memory");
  }
  bar();

  const int m7 = mrow & 7;
  const int aslot0 = (quad ^ m7) * 8;          // ks=0 slot; ks=1: ^32
  const int arow0 = (wm * 128 + mrow) * 64;    // A mh-local0 row base (elems)
  const int brow0 = (wn * 64 + mrow) * 64;     // B row base

  int cur = 0, nxt = 32768;
  short8 aC[4], bC[4];

  for (int T = 0; T < NT; ++T) {
    const unsigned short* As = smem + cur;
    const unsigned short* Bs = smem + cur + 16384;
    const int kt1 = (T + 1) << 6;
    const int kt2 = (T + 2) << 6;
    const bool m1 = (T + 1) < NT;
    const bool m2 = (T + 2) < NT;

    // ---------------- p0: A.mh0.ks0 x B.ks0 -> acc[0..3] ----------------
#pragma unroll
    for (int i = 0; i < 4; ++i)
      aC[i] = *(const short8*)(As + arow0 + i * 1024 + aslot0);
#pragma unroll
    for (int j = 0; j < 4; ++j)
      bC[j] = *(const short8*)(Bs + brow0 + j * 1024 + aslot0);
    if (m1) stgA(0, kt1, nxt);
    bar();
    asm volatile("s_waitcnt lgkmcnt(0)" ::: "memory");
    __builtin_amdgcn_sched_barrier(0);
    __builtin_amdgcn_s_setprio(1);
#pragma unroll
    for (int i = 0; i < 4; ++i)
#pragma unroll
      for (int j = 0; j < 4; ++j)
        acc[i][j] = __builtin_amdgcn_mfma_f32_16x16x32_bf16(aC[i], bC[j],
                                                            acc[i][j], 0, 0, 0);
    __builtin_amdgcn_s_setprio(0);
    __builtin_amdgcn_sched_barrier(0);

    // ---------------- p1: A.mh1.ks0 x B.ks0 -> acc[4..7] ----------------
#pragma unroll
    for (int i = 0; i < 4; ++i)
      aC[i] = *(const short8*)(As + arow0 + 4096 + i * 1024 + aslot0);
    if (m1) stgA(1, kt1, nxt);
    bar();
    asm volatile("s_waitcnt lgkmcnt(0)" ::: "memory");
    __builtin_amdgcn_sched_barrier(0);
    __builtin_amdgcn_s_setprio(1);
#pragma unroll
    for (int i = 0; i < 4; ++i)
#pragma unroll
      for (int j = 0; j < 4; ++j)
        acc[4 + i][j] = __builtin_amdgcn_mfma_f32_16x16x32_bf16(
            aC[i], bC[j], acc[4 + i][j], 0, 0, 0);
    __builtin_amdgcn_s_setprio(0);
    __builtin_amdgcn_sched_barrier(0);

    // ---------------- p2: A.mh0.ks1 x B.ks1 -> acc[0..3] ----------------
#pragma unroll
    for (int i = 0; i < 4; ++i)
      aC[i] = *(const short8*)(As + arow0 + i * 1024 + (aslot0 ^ 32));
#pragma unroll
    for (int j = 0; j < 4; ++j)
      bC[j] = *(const short8*)(Bs + brow0 + j * 1024 + (aslot0 ^ 32));
    if (m1) stgB(1, kt1, nxt);
    bar();
    asm volatile("s_waitcnt lgkmcnt(0)" ::: "memory");
    __builtin_amdgcn_sched_barrier(0);
    __builtin_amdgcn_s_setprio(1);
#pragma unroll
    for (int i = 0; i < 4; ++i)
#pragma unroll
      for (int j = 0; j < 4; ++j)
        acc[i][j] = __builtin_amdgcn_mfma_f32_16x16x32_bf16(aC[i], bC[j],
                                                            acc[i][j], 0, 0, 0);
    __builtin_amdgcn_s_setprio(0);
    __builtin_amdgcn_sched_barrier(0);

    // ---------------- p3: A.mh1.ks1 x B.ks1 -> acc[4..7] ----------------
#pragma unroll
    for (int i = 0; i < 4; ++i)
      aC[i] = *(const short8*)(As + arow0 + 4096 + i * 1024 + (aslot0 ^ 32));
    if (m2) stgB(0, kt2, cur);
    bar();
    asm volatile("s_waitcnt lgkmcnt(0)" ::: "memory");
    __builtin_amdgcn_sched_barrier(0);
    __builtin_amdgcn_s_setprio(1);
#pragma unroll
    for (int i = 0; i < 4; ++i)
#pragma unroll
      for (int j = 0; j < 4; ++j)
        acc[4 + i][j] = __builtin_amdgcn_mfma_f32_16x16x32_bf16(
            aC[i], bC[j], acc[4 + i][j], 0, 0, 0);
    __builtin_amdgcn_s_setprio(0);
    __builtin_amdgcn_sched_barrier(0);
    // tile boundary: collective landing of all of T+1's data
    if (m2) {
      asm volatile("s_waitcnt vmcnt(2)" ::: "memory");
    } else {
      asm volatile("s_waitcnt vmcnt(0)" ::: "memory");
    }
    bar();

    int tmp = cur; cur = nxt; nxt = tmp;
  }

  // -------------------- epilogue --------------------
  const long cb = (long)b * sC;

  if constexpr (MODE == 0) {
    if (bx < 8) {
      unsigned short* C = (unsigned short*)Cv;
#pragma unroll
      for (int m = 0; m < 8; ++m) {
        int row = rowA0 + wm * 128 + m * 16 + quad * 4;
#pragma unroll
        for (int j = 0; j < 4; ++j) {
          int col = rowB0 + wn * 64 + j * 16 + mrow;
#pragma unroll
          for (int r = 0; r < 4; ++r)
            C[(long)(row + r) * ldc + col] = f2bf(acc[m][j][r]);
        }
      }
    } else {
      // V: transpose via LDS (smem reused as [e 256][s 256] bf16, 128 KiB)
      // swz bits 3-6 only -> 4-aligned ushort4 writes / 8-aligned ushort8 reads
#pragma unroll
      for (int m = 0; m < 8; ++m) {
        int s4 = wm * 128 + m * 16 + quad * 4;
#pragma unroll
        for (int j = 0; j < 4; ++j) {
          int e = wn * 64 + j * 16 + mrow;
          int swz = ((e & 7) << 4) ^ (((e >> 3) & 3) << 3);
          ushort4 pk;
          pk.x = f2bf(acc[m][j][0]);
          pk.y = f2bf(acc[m][j][1]);
          pk.z = f2bf(acc[m][j][2]);
          pk.w = f2bf(acc[m][j][3]);
          *(ushort4*)(smem + e * 256 + (s4 ^ swz)) = pk;
        }
      }
      __syncthreads();
      const int batch = by >> 3;
      const int s_base = (by & 7) * 256;
      const int e_base = (bx - 8) * 256;
      unsigned short* VtB = Vt + (long)batch * 1024 * 2048;
      const int er = t >> 5;          // 0..15
      const int s = (t & 31) * 8;     // 0..248
#pragma unroll
      for (int rnd = 0; rnd < 16; ++rnd) {
        int e = rnd * 16 + er;
        int swz = ((e & 7) << 4) ^ (((e >> 3) & 3) << 3);
        ushort8 v = *(const ushort8*)(smem + e * 256 + (s ^ swz));
        *(ushort8*)(VtB + (long)(e_base + e) * 2048 + s_base + s) = v;
      }
    }
  } else {
    // MODE 1: E = exp(acc*alpha) -> bf16; row sums -> Lrow
    unsigned short* C = (unsigned short*)Cv;
    float p[8][4];
#pragma unroll
    for (int m = 0; m < 8; ++m)
#pragma unroll
      for (int r = 0; r < 4; ++r) p[m][r] = 0.f;
#pragma unroll
    for (int m = 0; m < 8; ++m) {
      int row = rowA0 + wm * 128 + m * 16 + quad * 4;
#pragma unroll
      for (int j = 0; j < 4; ++j) {
        int col = rowB0 + wn * 64 + j * 16 + mrow;
#pragma unroll
        for (int r = 0; r < 4; ++r) {
          float e = __expf(acc[m][j][r] * alpha);
          C[cb + (long)(row + r) * ldc + col] = f2bf(e);
          p[m][r] += e;
        }
      }
    }
#pragma unroll
    for (int off = 1; off < 16; off <<= 1)
#pragma unroll
      for (int m = 0; m < 8; ++m)
#pragma unroll
        for (int r = 0; r < 4; ++r)
          p[m][r] += __shfl_xor(p[m][r], off, 64);
    if (mrow == 0) {
#pragma unroll
      for (int m = 0; m < 8; ++m) {
        int row = rowA0 + wm * 128 + m * 16 + quad * 4;
#pragma unroll
        for (int r = 0; r < 4; ++r)
          atomicAdd(&Lrow[b * 2048 + row + r], p[m][r]);
      }
    }
  }
}

// ---------------------------------------------------------------- m97 body,
// kept for the out GEMM (MODE 2 only: fp32 store of acc/Lrow[row]).
template <int MODE>
__device__ __forceinline__ void gemm_body(
    const unsigned short* __restrict__ A, const unsigned short* __restrict__ B,
    void* __restrict__ Cv, int K, int lda, int ldb, int ldc,
    long sA, long sB, long sC, float alpha, float* __restrict__ Lrow,
    unsigned short* __restrict__ Vt) {
  constexpr int BM = 128, BN = 128, BK = 64;
  __shared__ __align__(16) unsigned short smem[BM * BK + BN * BK];  // 32 KB
  unsigned short* As = smem;
  unsigned short* Bs = smem + BM * BK;

  const int t = threadIdx.x;
  const int lane = t & 63;
  const int wave = t >> 6;
  const int quad = lane >> 4;
  const int mrow = lane & 15;
  const int wm = wave >> 1, wn = wave & 1;

  const int bx = blockIdx.x, by = blockIdx.y;
  const int rowA0 = by * BM;
  const int rowB0 = bx * BN;
  const int b = blockIdx.z;
  const unsigned short* Ab = A + (long)b * sA;
  const unsigned short* Bb = B + (long)b * sB;

  f32x4 acc[4][4];
#pragma unroll
  for (int i = 0; i < 4; ++i)
#pragma unroll
    for (int j = 0; j < 4; ++j) {
      f32x4 z = {0.f, 0.f, 0.f, 0.f};
      acc[i][j] = z;
    }

  const int rbase = wave * 32 + (lane >> 3);
  const int c2 = lane & 7;

  for (int kt = 0; kt < K; kt += BK) {
#pragma unroll
    for (int j = 0; j < 4; ++j) {
      int r = rbase + j * 8;
      int c = c2 ^ (r & 7);
      GLD_LDS16(Ab + (long)(rowA0 + r) * lda + kt + c * 8, As + (wave * 4 + j) * 512);
      GLD_LDS16(Bb + (long)(rowB0 + r) * ldb + kt + c * 8, Bs + (wave * 4 + j) * 512);
    }
    __syncthreads();
#pragma unroll
    for (int ks = 0; ks < 2; ++ks) {
      short8 af[4], bfr[4];
#pragma unroll
      for (int i = 0; i < 4; ++i) {
        int rA = wm * 64 + i * 16 + mrow;
        int cc = ks * 4 + quad;
        af[i] = *(const short8*)(As + (rA * 8 + (cc ^ (rA & 7))) * 8);
        int rB = wn * 64 + i * 16 + mrow;
        bfr[i] = *(const short8*)(Bs + (rB * 8 + (cc ^ (rB & 7))) * 8);
      }
#pragma unroll
      for (int mt = 0; mt < 4; ++mt)
#pragma unroll
        for (int nt = 0; nt < 4; ++nt)
          acc[mt][nt] = __builtin_amdgcn_mfma_f32_16x16x32_bf16(
              af[mt], bfr[nt], acc[mt][nt], 0, 0, 0);
    }
    __syncthreads();
  }

  const int m_base = rowA0 + wm * 64;
  const int n_base = rowB0 + wn * 64;
  const long cb = (long)b * sC;

  // MODE 2 only instantiated: fp32 out, scaled by 1/Lrow[row]
#pragma unroll
  for (int mt = 0; mt < 4; ++mt)
#pragma unroll
    for (int i = 0; i < 4; ++i) {
      int row = m_base + mt * 16 + quad * 4 + i;
      float inv = 1.0f / Lrow[b * 2048 + row];
#pragma unroll
      for (int nt = 0; nt < 4; ++nt) {
        int col = n_base + nt * 16 + mrow;
        ((float*)Cv)[cb + (long)row * ldc + col] = acc[mt][nt][i] * inv;
      }
    }
}

// distinct names so rocprof separates the three GEMMs
__global__ __launch_bounds__(512, 2) void qkv_gemm_kernel(
    const unsigned short* __restrict__ A, const unsigned short* __restrict__ B,
    void* __restrict__ Cv, int K, int lda, int ldb, int ldc,
    long sA, long sB, long sC, float alpha, float* __restrict__ Lrow,
    unsigned short* __restrict__ Vt) {
  gemm256_body<0>(A, B, Cv, K, lda, ldb, ldc, sA, sB, sC, alpha, Lrow, Vt);
}
__global__ __launch_bounds__(512, 2) void score_gemm_kernel(
    const unsigned short* __restrict__ A, const unsigned short* __restrict__ B,
    void* __restrict__ Cv, int K, int lda, int ldb, int ldc,
    long sA, long sB, long sC, float alpha, float* __restrict__ Lrow,
    unsigned short* __restrict__ Vt) {
  gemm256_body<1>(A, B, Cv, K, lda, ldb, ldc, sA, sB, sC, alpha, Lrow, Vt);
}
__global__ __launch_bounds__(256, 2) void out_gemm_kernel(
    const unsigned short* __restrict__ A, const unsigned short* __restrict__ B,
    void* __restrict__ Cv, int K, int lda, int ldb, int ldc,
    long sA, long sB, long sC, float alpha, float* __restrict__ Lrow,
    unsigned short* __restrict__ Vt) {
  gemm_body<2>(A, B, Cv, K, lda, ldb, ldc, sA, sB, sC, alpha, Lrow, Vt);
}

// ---------------------------------------------------------------- launch
extern "C" void kernel_launch(void* const* d_in, const int* in_sizes, int n_in,
                              void* d_out, int out_size, void* d_ws, size_t ws_size,
                              hipStream_t stream) {
  const float* X = (const float*)d_in[0];  // [4,2048,1024] fp32
  const float* W = (const float*)d_in[1];  // [1024,3072] fp32
  float* out = (float*)d_out;              // [4,2048,1024] fp32

  char* ws = (char*)d_ws;
  unsigned short* Xb  = (unsigned short*)(ws);                 // 8192x1024 bf16   (16 MiB)
  unsigned short* Wtb = (unsigned short*)(ws + 16777216);      // 3072x1024 bf16   ( 6 MiB)
  unsigned short* QK  = (unsigned short*)(ws + 23068672);      // 8192x2048 bf16   (32 MiB)
  unsigned short* Vt  = (unsigned short*)(ws + 56623104);      // 4x1024x2048 bf16 (16 MiB)
  unsigned short* Sb  = (unsigned short*)(ws + 73400320);      // 4x2048x2048 bf16 (32 MiB)
  float* Lrow         = (float*)(ws + 106954752);              // 4x2048 fp32      (32 KiB)

  // 1. prep: cast X, transpose W, zero Lrow
  prep_kernel<<<4865, 256, 0, stream>>>(X, Xb, W, Wtb, Lrow);

  // 2. [Q|K] = Xb @ Wtb^T  (bx<8 -> QK, ldc=2048); V -> Vt transposed (bx>=8)
  qkv_gemm_kernel<<<dim3(12, 32, 1), 512, 0, stream>>>(
      Xb, Wtb, QK, 1024, 1024, 1024, 2048, 0L, 0L, 0L, 1.0f, nullptr, Vt);

  // 3. E = exp(Q @ K^T / 32) per batch [2048 x 2048], K=1024; row sums -> Lrow
  score_gemm_kernel<<<dim3(8, 8, 4), 512, 0, stream>>>(
      QK, QK + 1024, Sb, 1024, 2048, 2048, 2048,
      (long)2048 * 2048, (long)2048 * 2048, (long)2048 * 2048, 0.03125f, Lrow, nullptr);

  // 4. O = (E @ Vt^T) / L  per batch  [2048 x 1024], K=2048 -> fp32 out
  out_gemm_kernel<<<dim3(8, 16, 4), 256, 0, stream>>>(
      Sb, Vt, out, 2048, 2048, 2048, 1024,
      (long)2048 * 2048, (long)1024 * 2048, (long)2048 * 1024, 1.0f, Lrow, nullptr);
}